// Round 4
// baseline (197.441 us; speedup 1.0000x reference)
//
#include <hip/hip_runtime.h>
#include <math.h>

#define B_TOT 2048
#define R_TOT 512
#define D_TOT 256
#define LOG2E 1.4426950408889634f
#define SCALE_C 2.220446049250313e-16f   // 2^-52, exact

typedef float vf4 __attribute__((ext_vector_type(4)));
typedef float vf2 __attribute__((ext_vector_type(2)));

// pp layout: [r][32 groups of 8 d][24] = {A0..7, Bc0..7, Ms0..7}
// Ms = m1 * 2^-52 at j==0 and j==4 (folds the overflow-scaling for the
// 8-wide rcp group; numerator and denominator carry the same 2^-104 so the
// ratio is exact).  gated = (1+m1*e)/(1+e), e = exp2(A*x+Bc).

__global__ void prep_kernel(const float* __restrict__ th,
                            const float* __restrict__ sp,
                            const float* __restrict__ ml,
                            const float* __restrict__ lk,
                            float* __restrict__ pp) {
    int idx = blockIdx.x * 256 + threadIdx.x;   // r*256 + d
    if (idx >= R_TOT * D_TOT) return;
    float kmul = -LOG2E * __builtin_amdgcn_exp2f(lk[0] * LOG2E);
    float u  = sp[idx];
    float eu = __builtin_amdgcn_exp2f(2.0f * LOG2E * u);
    float t  = 1.0f - 2.0f * __builtin_amdgcn_rcpf(eu + 1.0f);
    float A  = kmul * t;
    float Bc = -A * th[idx];
    float em = __builtin_amdgcn_exp2f(LOG2E * ml[idx]);
    float m1 = __builtin_amdgcn_rcpf(1.0f + em);
    int r = idx >> 8, d = idx & 255;
    int g = d >> 3, j = d & 7;
    float* base = pp + ((size_t)r * 32 + g) * 24;
    base[j]      = A;
    base[8 + j]  = Bc;
    base[16 + j] = m1 * ((j == 0 || j == 4) ? SCALE_C : 1.0f);
}

// ---------------------------------------------------------------------------
// Main: WG = 256 thr = 4 waves; 64 batches x 4 rules (1 rule/wave).
// grid 128x32 = 4096 WGs = 2 rounds of 8 WG/CU (32 waves/CU).
// x tile (64b x 64d) lives in LDS b-major with XOR-swizzled 16B columns:
//   xs4[b][col] holds chunk c = col ^ (b&15)  ->  ds_read_b128 conflict-free.
// Params arrive via uniform-address VECTOR loads (VGPR) so the packed-f32
// VOP3P ops have no SGPR-operand restriction.
// ---------------------------------------------------------------------------
__global__ __launch_bounds__(256, 8) void main_kernel(
        const float* __restrict__ x,       // [B_TOT][D_TOT]
        const float* __restrict__ pp,      // [R_TOT][32][24]
        const float* __restrict__ head_w,  // [R_TOT]
        const float* __restrict__ head_b,  // [1]
        float*       __restrict__ y) {     // [B_TOT]
    __shared__ __align__(16) float xs[64 * 64];   // 16 KB
    __shared__ float red[256];

    const int tid  = threadIdx.x;
    const int lane = tid & 63;
    const int wave = tid >> 6;                 // intentionally not scalarized
    const int rg   = blockIdx.x;               // 0..127
    const int bg   = blockIdx.y;               // 0..31
    const int b0   = bg << 6;
    const int r0   = (rg << 2) + wave;         // this wave's rule

    const int s      = lane & 15;
    const int lane64 = lane << 6;              // lane * 64 floats

    // Per-thread staging coords (constant across tiles):
    //   i = it*256 + tid ; b = i>>4 ; c = i&15
    int sb[4], sc[4], su[4];
    #pragma unroll
    for (int it = 0; it < 4; it++) {
        int i  = it * 256 + tid;
        sb[it] = i >> 4;
        sc[it] = i & 15;
        su[it] = (sb[it] << 4) + (sc[it] ^ (sb[it] & 15));   // 16B-unit index
    }

    const vf4* x4 = (const vf4*)x;
    vf4 st[4];
    #pragma unroll
    for (int it = 0; it < 4; it++)
        st[it] = x4[(size_t)(b0 + sb[it]) * 16 /*D/16*/ * 4 / 4
                    + (size_t)(b0 + sb[it]) * 0 + (b0 + sb[it]) * 0
                    + (size_t)(b0 + sb[it]) * 0];  // placeholder overwritten below
    // (real preload, tile 0)
    #pragma unroll
    for (int it = 0; it < 4; it++)
        st[it] = x4[(size_t)(b0 + sb[it]) * (D_TOT / 4) + 0 * 16 + sc[it]];

    const vf4 K = {SCALE_C, 1.0f, 1.0f, 1.0f};
    float acc = 1.0f;

    #pragma unroll
    for (int dt = 0; dt < 4; dt++) {
        __syncthreads();
        // write staged regs for this tile (balanced ds_write_b128)
        #pragma unroll
        for (int it = 0; it < 4; it++)
            *(vf4*)&xs[su[it] << 2] = st[it];
        // prefetch next tile into registers during this tile's compute
        if (dt < 3) {
            #pragma unroll
            for (int it = 0; it < 4; it++)
                st[it] = x4[(size_t)(b0 + sb[it]) * (D_TOT / 4)
                            + (dt + 1) * 16 + sc[it]];
        }
        __syncthreads();

        #pragma unroll 2
        for (int g = 0; g < 8; g++) {
            const float* Pf = pp + ((size_t)r0 * 32 + dt * 8 + g) * 24;
            vf4 a0  = *(const vf4*)(Pf);
            vf4 a1  = *(const vf4*)(Pf + 4);
            vf4 bb0 = *(const vf4*)(Pf + 8);
            vf4 bb1 = *(const vf4*)(Pf + 12);
            vf4 m0v = *(const vf4*)(Pf + 16);
            vf4 m1v = *(const vf4*)(Pf + 20);

            int col0 = (g << 1) ^ s;
            vf4 xA = *(const vf4*)&xs[lane64 + (col0 << 2)];
            vf4 xB = *(const vf4*)&xs[lane64 + ((col0 ^ 1) << 2)];

            vf4 t0 = a0 * xA + bb0;
            vf4 t1 = a1 * xB + bb1;
            vf4 e0, e1;
            e0.x = __builtin_amdgcn_exp2f(t0.x);
            e0.y = __builtin_amdgcn_exp2f(t0.y);
            e0.z = __builtin_amdgcn_exp2f(t0.z);
            e0.w = __builtin_amdgcn_exp2f(t0.w);
            e1.x = __builtin_amdgcn_exp2f(t1.x);
            e1.y = __builtin_amdgcn_exp2f(t1.y);
            e1.z = __builtin_amdgcn_exp2f(t1.z);
            e1.w = __builtin_amdgcn_exp2f(t1.w);

            vf4 n0  = m0v * e0 + K;          // numerator factors (scaled)
            vf4 n1  = m1v * e1 + K;
            vf4 dd0 = e0 * K + K;            // denominator factors (scaled)
            vf4 dd1 = e1 * K + K;

            vf4 pn = n0 * n1;
            vf4 pd = dd0 * dd1;
            vf2 hn = pn.lo * pn.hi;
            vf2 hd = pd.lo * pd.hi;
            float num = hn.x * hn.y;
            float den = hd.x * hd.y;
            acc *= num * __builtin_amdgcn_rcpf(den);
        }
    }

    // ---- head: partial = w[r0] * z for this lane's batch ----
    float partial = head_w[r0] * acc;
    red[tid] = partial;
    __syncthreads();
    if (wave == 0) {
        float t = red[lane] + red[64 + lane] + red[128 + lane] + red[192 + lane];
        if (rg == 0) t += head_b[0];         // bias exactly once per batch
        atomicAdd(&y[b0 + lane], t);
    }
}

extern "C" void kernel_launch(void* const* d_in, const int* in_sizes, int n_in,
                              void* d_out, int out_size, void* d_ws, size_t ws_size,
                              hipStream_t stream) {
    const float* x  = (const float*)d_in[0];
    const float* th = (const float*)d_in[1];
    const float* sp = (const float*)d_in[2];
    const float* ml = (const float*)d_in[3];
    const float* lk = (const float*)d_in[4];
    const float* hw = (const float*)d_in[5];
    const float* hb = (const float*)d_in[6];
    float* y = (float*)d_out;

    float* pp = (float*)d_ws;   // 512*32*24 floats = 1.5 MB

    hipMemsetAsync(y, 0, (size_t)out_size * sizeof(float), stream);
    prep_kernel<<<(R_TOT * D_TOT + 255) / 256, 256, 0, stream>>>(th, sp, ml, lk, pp);
    dim3 grid(128, 32, 1);
    main_kernel<<<grid, 256, 0, stream>>>(x, pp, hw, hb, y);
}

// Round 5
// 126.071 us; speedup vs baseline: 1.5661x; 1.5661x over previous
//
#include <hip/hip_runtime.h>
#include <math.h>

#define B_TOT 2048
#define R_TOT 512
#define D_TOT 256
#define LOG2E 1.4426950408889634f
#define SCALE_C 2.220446049250313e-16f   // 2^-52 exact

typedef float vf4 __attribute__((ext_vector_type(4)));
typedef float vf2 __attribute__((ext_vector_type(2)));

// gated = (1 + m1*e)/(1 + e),  e = exp2(A*x + Bc)
// A = -log2e*kappa*tanh(sign), Bc = -A*th, m1 = 1 - sigmoid(mask)
// Param planes: ppA[r*256+d], ppB[r*256+d], ppM[r*256+d].
// ppM carries 2^-52 folded at d%8==0 (once per 8-d lane-pair group) so the
// per-8d rcp group's num/den both carry the same scale -> ratio exact.

__global__ void prep_kernel(const float* __restrict__ th,
                            const float* __restrict__ sp,
                            const float* __restrict__ ml,
                            const float* __restrict__ lk,
                            float* __restrict__ pp) {
    int idx = blockIdx.x * 256 + threadIdx.x;   // r*256 + d
    if (idx >= R_TOT * D_TOT) return;
    float kmul = -LOG2E * __builtin_amdgcn_exp2f(lk[0] * LOG2E);
    float u  = sp[idx];
    float eu = __builtin_amdgcn_exp2f(2.0f * LOG2E * u);
    float t  = 1.0f - 2.0f * __builtin_amdgcn_rcpf(eu + 1.0f);
    float A  = kmul * t;
    float Bc = -A * th[idx];
    float em = __builtin_amdgcn_exp2f(LOG2E * ml[idx]);
    float m1 = __builtin_amdgcn_rcpf(1.0f + em);
    int d = idx & 255;
    pp[idx]                       = A;
    pp[R_TOT * D_TOT + idx]       = Bc;
    pp[2 * R_TOT * D_TOT + idx]   = m1 * (((d & 7) == 0) ? SCALE_C : 1.0f);
}

// lane^1 swap via DPP quad_perm [1,0,3,2] = 0xB1 (pure VALU, no LDS)
static __device__ __forceinline__ float pair_swap(float v) {
    int i = __builtin_amdgcn_mov_dpp(__float_as_int(v), 0xB1, 0xF, 0xF, true);
    return __int_as_float(i);
}

// ---------------------------------------------------------------------------
// Main: WG = 256 = 4 waves. wave -> 1 rule; WG -> 4 rules x 16 batches.
// lane l owns d = 4l..4l+3; params live in 12 VGPRs for the whole kernel.
// Per batch: x via one coalesced dwordx4 (L1/L2), packed math, 4 exp2,
// 8-d pair ratio with one rcp. End: LDS transpose, per-batch product,
// head dot, one atomicAdd per (WG,batch).
// grid = (512/4 rules, 2048/16 batches) = 128 x 128.
// ---------------------------------------------------------------------------
__global__ __launch_bounds__(256, 4) void main_kernel(
        const float* __restrict__ x,       // [B_TOT][D_TOT]
        const float* __restrict__ pp,      // 3 planes of [R_TOT][D_TOT]
        const float* __restrict__ head_w,  // [R_TOT]
        const float* __restrict__ head_b,  // [1]
        float*       __restrict__ y) {     // [B_TOT]
    __shared__ float rbuf[4][16][36];      // pad 36: 16B-aligned, <=2-way banks
    __shared__ float wz[4][16];

    const int tid  = threadIdx.x;
    const int lane = tid & 63;
    const int wave = tid >> 6;
    const int r0   = (blockIdx.x << 2) + wave;   // this wave's rule
    const int b0   = blockIdx.y << 4;            // 16 batches

    // ---- params: one coalesced vf4 load per plane, held in VGPRs ----
    const vf4* pA = (const vf4*)pp                         + r0 * 64 + lane;
    const vf4* pB = (const vf4*)(pp + R_TOT * D_TOT)       + r0 * 64 + lane;
    const vf4* pM = (const vf4*)(pp + 2 * R_TOT * D_TOT)   + r0 * 64 + lane;
    vf4 A  = *pA;
    vf4 Bc = *pB;
    vf4 Ms = *pM;
    const float kx = (lane & 1) ? 1.0f : SCALE_C;
    const vf4 K = {kx, 1.0f, 1.0f, 1.0f};

    const vf4* xv = (const vf4*)x + (size_t)b0 * 64 + lane;

    float r8[16];
    #pragma unroll
    for (int b = 0; b < 16; b++) {
        vf4 xb = xv[b * 64];                 // coalesced 1 KB/wave, L1/L2 hit
        vf4 t  = A * xb + Bc;                // v_pk_fma_f32
        vf4 e;
        e.x = __builtin_amdgcn_exp2f(t.x);
        e.y = __builtin_amdgcn_exp2f(t.y);
        e.z = __builtin_amdgcn_exp2f(t.z);
        e.w = __builtin_amdgcn_exp2f(t.w);
        vf4 n  = Ms * e + K;                 // scaled numerator factors
        vf4 dd = e * K + K;                  // scaled denominator factors
        vf2 hn = n.lo * n.hi;
        vf2 hd = dd.lo * dd.hi;
        float np = hn.x * hn.y;              // lane's 4-d num product
        float dp = hd.x * hd.y;
        float np8 = np * pair_swap(np);      // 8-d group (lane pair)
        float dp8 = dp * pair_swap(dp);
        r8[b] = np8 * __builtin_amdgcn_rcpf(dp8);   // in [0.6^8, 1]
    }

    // ---- end-phase: transpose ratios through LDS, product per batch ----
    if (!(lane & 1)) {
        #pragma unroll
        for (int b = 0; b < 16; b++)
            rbuf[wave][b][lane >> 1] = r8[b];
    }
    __syncthreads();

    if (lane < 16) {
        const float* rb = &rbuf[wave][lane][0];
        vf4 a0 = *(const vf4*)(rb)      * *(const vf4*)(rb + 4);
        vf4 a1 = *(const vf4*)(rb + 8)  * *(const vf4*)(rb + 12);
        vf4 a2 = *(const vf4*)(rb + 16) * *(const vf4*)(rb + 20);
        vf4 a3 = *(const vf4*)(rb + 24) * *(const vf4*)(rb + 28);
        vf4 m  = (a0 * a1) * (a2 * a3);
        vf2 h  = m.lo * m.hi;
        float z = h.x * h.y;                 // z(b, r0)
        wz[wave][lane] = head_w[r0] * z;
    }
    __syncthreads();

    if (wave == 0 && lane < 16) {
        float s = wz[0][lane] + wz[1][lane] + wz[2][lane] + wz[3][lane];
        if (blockIdx.x == 0) s += head_b[0];   // bias exactly once per batch
        atomicAdd(&y[b0 + lane], s);
    }
}

extern "C" void kernel_launch(void* const* d_in, const int* in_sizes, int n_in,
                              void* d_out, int out_size, void* d_ws, size_t ws_size,
                              hipStream_t stream) {
    const float* x  = (const float*)d_in[0];
    const float* th = (const float*)d_in[1];
    const float* sp = (const float*)d_in[2];
    const float* ml = (const float*)d_in[3];
    const float* lk = (const float*)d_in[4];
    const float* hw = (const float*)d_in[5];
    const float* hb = (const float*)d_in[6];
    float* y = (float*)d_out;

    float* pp = (float*)d_ws;   // 3 * 512 * 256 floats = 1.5 MB

    hipMemsetAsync(y, 0, (size_t)out_size * sizeof(float), stream);
    prep_kernel<<<R_TOT, 256, 0, stream>>>(th, sp, ml, lk, pp);
    dim3 grid(R_TOT / 4, B_TOT / 16, 1);
    main_kernel<<<grid, 256, 0, stream>>>(x, pp, hw, hb, y);
}